// Round 2
// baseline (1574.595 us; speedup 1.0000x reference)
//
#include <hip/hip_runtime.h>
#include <hip/hip_bf16.h>
#include <math.h>

#define NN 100000
#define NE 1000000

// ---------------- degree / CSR build ----------------

__global__ void count_kernel(const int* __restrict__ dst, int* __restrict__ cnt, int n) {
    int e = blockIdx.x * blockDim.x + threadIdx.x;
    if (e < n) atomicAdd(&cnt[dst[e]], 1);
}

__global__ void dinv_kernel(const int* __restrict__ cnt, float* __restrict__ dinv, int n) {
    int v = blockIdx.x * blockDim.x + threadIdx.x;
    if (v < n) dinv[v] = 1.0f / sqrtf((float)cnt[v] + 1.0f);  // +1 self-loop
}

// single-block exclusive scan over n elements (n up to ~100k)
__global__ void scan_kernel(const int* __restrict__ cnt, int* __restrict__ rp, int n) {
    __shared__ int sh[1024];
    __shared__ int run;
    int t = threadIdx.x;
    if (t == 0) run = 0;
    __syncthreads();
    for (int base = 0; base < n; base += 1024) {
        int v = (base + t < n) ? cnt[base + t] : 0;
        sh[t] = v;
        __syncthreads();
        for (int off = 1; off < 1024; off <<= 1) {
            int a = (t >= off) ? sh[t - off] : 0;
            __syncthreads();
            sh[t] += a;
            __syncthreads();
        }
        int incl = sh[t];
        if (base + t < n) rp[base + t] = run + incl - v;   // exclusive
        __syncthreads();
        if (t == 1023) run += incl;   // incl of t=1023 == chunk total
        __syncthreads();
    }
    __syncthreads();
    if (t == 0) rp[n] = run;
}

__global__ void fill_kernel(const int* __restrict__ src, const int* __restrict__ dst,
                            const int* __restrict__ rp, int* __restrict__ fill,
                            int* __restrict__ csrc, int n) {
    int e = blockIdx.x * blockDim.x + threadIdx.x;
    if (e < n) {
        int d = dst[e];
        int pos = rp[d] + atomicAdd(&fill[d], 1);
        csrc[pos] = src[e];
    }
}

// ---------------- GEMM1: h1 = x @ W1  (M=100000, K=500, N=256) ----------------
#define BM 64
#define BN 64
#define BK 16

__launch_bounds__(256)
__global__ void gemm1_kernel(const float* __restrict__ A, const float* __restrict__ B,
                             float* __restrict__ C, int M, int K, int N) {
    __shared__ float As[BM][BK + 1];
    __shared__ float Bs[BK][BN];
    int t = threadIdx.x;
    int bm = blockIdx.x * BM;
    int bn = blockIdx.y * BN;
    int tx = t & 15, ty = t >> 4;
    float acc[4][4] = {};
    for (int k0 = 0; k0 < K; k0 += BK) {
        {   // stage A tile 64x16 (4 scalars per thread)
            int r = t >> 2;
            int kk = (t & 3) * 4;
            int row = bm + r;
#pragma unroll
            for (int i = 0; i < 4; i++) {
                int k = k0 + kk + i;
                As[r][kk + i] = (row < M && k < K) ? A[(size_t)row * K + k] : 0.f;
            }
        }
#pragma unroll
        for (int i = 0; i < 4; i++) {  // stage B tile 16x64
            int kk = (t >> 6) + i * 4;
            int n = t & 63;
            int k = k0 + kk;
            Bs[kk][n] = (k < K) ? B[(size_t)k * N + bn + n] : 0.f;
        }
        __syncthreads();
#pragma unroll
        for (int kk = 0; kk < BK; kk++) {
            float a[4], b[4];
#pragma unroll
            for (int i = 0; i < 4; i++) a[i] = As[ty * 4 + i][kk];
#pragma unroll
            for (int j = 0; j < 4; j++) b[j] = Bs[kk][tx * 4 + j];
#pragma unroll
            for (int i = 0; i < 4; i++)
#pragma unroll
                for (int j = 0; j < 4; j++) acc[i][j] += a[i] * b[j];
        }
        __syncthreads();
    }
#pragma unroll
    for (int i = 0; i < 4; i++) {
        int row = bm + ty * 4 + i;
        if (row < M) {
#pragma unroll
            for (int j = 0; j < 4; j++)
                C[(size_t)row * N + bn + tx * 4 + j] = acc[i][j];
        }
    }
}

// ---------------- aggregation layer 1 (256 cols, wave per node, float4/lane) ----------------
__global__ void agg1_kernel(const float* __restrict__ h, const float* __restrict__ dinv,
                            const int* __restrict__ rp, const int* __restrict__ csrc,
                            const float* __restrict__ bias, float* __restrict__ out, int n) {
    int wave = (blockIdx.x * blockDim.x + threadIdx.x) >> 6;
    int lane = threadIdx.x & 63;
    if (wave >= n) return;
    int v = wave;
    float dv = dinv[v];
    float4 acc = ((const float4*)(h + (size_t)v * 256))[lane];
    acc.x *= dv; acc.y *= dv; acc.z *= dv; acc.w *= dv;  // self-loop: h[v]*dinv[v]
    int b0 = rp[v], b1e = rp[v + 1];
    for (int i = b0; i < b1e; i++) {
        int s = csrc[i];
        float ds = dinv[s];
        float4 hs = ((const float4*)(h + (size_t)s * 256))[lane];
        acc.x += hs.x * ds; acc.y += hs.y * ds; acc.z += hs.z * ds; acc.w += hs.w * ds;
    }
    float4 bb = ((const float4*)bias)[lane];
    float4 o;
    o.x = fmaxf(acc.x * dv + bb.x, 0.f);
    o.y = fmaxf(acc.y * dv + bb.y, 0.f);
    o.z = fmaxf(acc.z * dv + bb.z, 0.f);
    o.w = fmaxf(acc.w * dv + bb.w, 0.f);
    ((float4*)(out + (size_t)v * 256))[lane] = o;
}

// ---------------- GEMM2: h2 = h1a @ W2 (K=256 -> N=64), W2 fully in LDS ----------------
__global__ void gemm2_kernel(const float* __restrict__ X, const float* __restrict__ W2,
                             float* __restrict__ Y, int n) {
    extern __shared__ float smem[];
    float* W2s = smem;             // 256*64
    float* rows = smem + 256 * 64; // 4 * 260
    int t = threadIdx.x;
    for (int i = t; i < 256 * 64; i += 256) W2s[i] = W2[i];
    __syncthreads();
    int wv = t >> 6, lane = t & 63;
    float* myrow = rows + wv * 260;
    for (int v = blockIdx.x * 4 + wv; v < n; v += gridDim.x * 4) {
        float4 rv = ((const float4*)(X + (size_t)v * 256))[lane];
        ((float4*)myrow)[lane] = rv;
        float acc = 0.f;
        const float4* r4 = (const float4*)myrow;
#pragma unroll 8
        for (int k4 = 0; k4 < 64; k4++) {
            float4 rk = r4[k4];
            acc += rk.x * W2s[(k4 * 4 + 0) * 64 + lane];
            acc += rk.y * W2s[(k4 * 4 + 1) * 64 + lane];
            acc += rk.z * W2s[(k4 * 4 + 2) * 64 + lane];
            acc += rk.w * W2s[(k4 * 4 + 3) * 64 + lane];
        }
        Y[(size_t)v * 64 + lane] = acc;
    }
}

// ---------------- aggregation layer 2 (64 cols, wave per node, scalar/lane) ----------------
__global__ void agg2_kernel(const float* __restrict__ h, const float* __restrict__ dinv,
                            const int* __restrict__ rp, const int* __restrict__ csrc,
                            const float* __restrict__ bias, float* __restrict__ out, int n) {
    int wave = (blockIdx.x * blockDim.x + threadIdx.x) >> 6;
    int lane = threadIdx.x & 63;
    if (wave >= n) return;
    int v = wave;
    float dv = dinv[v];
    float acc = h[(size_t)v * 64 + lane] * dv;
    int b0 = rp[v], b1e = rp[v + 1];
    for (int i = b0; i < b1e; i++) {
        int s = csrc[i];
        acc += h[(size_t)s * 64 + lane] * dinv[s];
    }
    out[(size_t)v * 64 + lane] = fmaxf(acc * dv + bias[lane], 0.f);
}

// ---------------- heads: p[v] = h@WW ; biases[v] = h@WB + bB ----------------
__global__ void heads_kernel(const float* __restrict__ h, const float* __restrict__ WW,
                             const float* __restrict__ WB, const float* __restrict__ bB,
                             float* __restrict__ p, float* __restrict__ outB, int n) {
    int wave = (blockIdx.x * blockDim.x + threadIdx.x) >> 6;
    int lane = threadIdx.x & 63;
    if (wave >= n) return;
    int v = wave;
    float hv = h[(size_t)v * 64 + lane];
    float pw = hv * WW[lane];
    float pb = hv * WB[lane];
#pragma unroll
    for (int off = 32; off >= 1; off >>= 1) {
        pw += __shfl_xor(pw, off);
        pb += __shfl_xor(pb, off);
    }
    if (lane == 0) {
        p[v] = pw;
        outB[v] = pb + bB[0];
    }
}

__global__ void weights_kernel(const int* __restrict__ src, const int* __restrict__ dst,
                               const float* __restrict__ p, const float* __restrict__ bW,
                               float* __restrict__ outW, int n) {
    int i = blockIdx.x * blockDim.x + threadIdx.x;
    if (i < n) {
        int e = 2 * i;
        outW[i] = 0.5f * (p[src[e]] + p[dst[e]]) + bW[0];
    }
}

// ---------------- launch ----------------

extern "C" void kernel_launch(void* const* d_in, const int* in_sizes, int n_in,
                              void* d_out, int out_size, void* d_ws, size_t ws_size,
                              hipStream_t stream) {
    const float* x  = (const float*)d_in[0];
    const int*   ei = (const int*)d_in[1];
    const int*   src = ei;
    const int*   dst = ei + NE;
    const float* W1 = (const float*)d_in[2];
    const float* b1 = (const float*)d_in[3];
    const float* W2 = (const float*)d_in[4];
    const float* b2 = (const float*)d_in[5];
    const float* WB = (const float*)d_in[6];
    const float* bB = (const float*)d_in[7];
    const float* WW = (const float*)d_in[8];
    const float* bW = (const float*)d_in[9];
    float* outW = (float*)d_out;          // 500000 weights
    float* outB = (float*)d_out + 500000; // 100000 biases

    char* ws = (char*)d_ws;
    // region A: h1 (100000*256 f32 = 102,400,000 B); later reused for h2/h2a/p
    float* h1  = (float*)(ws);
    float* h1a = (float*)(ws + 102400000);           // region B
    float* h2  = (float*)(ws);                       // overlays dead h1
    float* h2a = (float*)(ws + 25600000);
    float* p   = (float*)(ws + 51200000);
    char* tail = ws + 204800000;
    float* dinv = (float*)(tail);                    // 100000 f32
    int*   rp   = (int*)(tail + 400000);             // 100001 int
    int*   cnt  = (int*)(tail + 800064);             // 100000 int
    int*   fill = (int*)(tail + 1200064);            // 100000 int
    int*   csrc = (int*)(tail + 1600064);            // 1,000,000 int

    hipMemsetAsync(cnt, 0, 800000, stream);  // cnt + fill (contiguous)

    count_kernel<<<(NE + 255) / 256, 256, 0, stream>>>(dst, cnt, NE);
    dinv_kernel<<<(NN + 255) / 256, 256, 0, stream>>>(cnt, dinv, NN);
    scan_kernel<<<1, 1024, 0, stream>>>(cnt, rp, NN);
    fill_kernel<<<(NE + 255) / 256, 256, 0, stream>>>(src, dst, rp, fill, csrc, NE);

    gemm1_kernel<<<dim3((NN + BM - 1) / BM, 256 / BN), 256, 0, stream>>>(x, W1, h1, NN, 500, 256);
    agg1_kernel<<<(NN + 3) / 4, 256, 0, stream>>>(h1, dinv, rp, csrc, b1, h1a, NN);

    size_t g2lds = (256 * 64 + 4 * 260) * sizeof(float);
    gemm2_kernel<<<512, 256, g2lds, stream>>>(h1a, W2, h2, NN);
    agg2_kernel<<<(NN + 3) / 4, 256, 0, stream>>>(h2, dinv, rp, csrc, b2, h2a, NN);

    heads_kernel<<<(NN + 3) / 4, 256, 0, stream>>>(h2a, WW, WB, bB, p, outB, NN);
    weights_kernel<<<(500000 + 255) / 256, 256, 0, stream>>>(src, dst, p, bW, outW, 500000);
}

// Round 5
// 938.889 us; speedup vs baseline: 1.6771x; 1.6771x over previous
//
#include <hip/hip_runtime.h>
#include <hip/hip_bf16.h>
#include <math.h>

#define NN 100000
#define NE 1000000

typedef __attribute__((ext_vector_type(8))) short bf16x8;
typedef __attribute__((ext_vector_type(4))) float f32x4;

__device__ __forceinline__ unsigned short f2bf(float f) {
    unsigned int u = __builtin_bit_cast(unsigned int, f);
    unsigned int r = (u + 0x7fff + ((u >> 16) & 1)) >> 16;   // RNE
    return (unsigned short)r;
}
__device__ __forceinline__ float bf2f(unsigned short s) {
    unsigned int u = ((unsigned int)s) << 16;
    return __builtin_bit_cast(float, u);
}

// ---------------- degree / CSR build ----------------

__global__ void count_kernel(const int* __restrict__ dst, int* __restrict__ cnt, int n) {
    int e = blockIdx.x * blockDim.x + threadIdx.x;
    if (e < n) atomicAdd(&cnt[dst[e]], 1);
}

__global__ void dinv_kernel(const int* __restrict__ cnt, float* __restrict__ dinv, int n) {
    int v = blockIdx.x * blockDim.x + threadIdx.x;
    if (v < n) dinv[v] = 1.0f / sqrtf((float)cnt[v] + 1.0f);  // +1 self-loop
}

// parallel scan: per-chunk inclusive (scan1) -> chunk sums exclusive (scan2) -> combine (scan3)
__global__ void scan1_kernel(const int* __restrict__ cnt, int* __restrict__ tmp,
                             int* __restrict__ bsum, int n) {
    __shared__ int sh[1024];
    int t = threadIdx.x;
    int i = blockIdx.x * 1024 + t;
    int v = (i < n) ? cnt[i] : 0;
    sh[t] = v;
    __syncthreads();
    for (int off = 1; off < 1024; off <<= 1) {
        int a = (t >= off) ? sh[t - off] : 0;
        __syncthreads();
        sh[t] += a;
        __syncthreads();
    }
    if (i < n) tmp[i] = sh[t];
    if (t == 1023) bsum[blockIdx.x] = sh[t];
}

__global__ void scan2_kernel(int* __restrict__ bsum, int nb) {
    __shared__ int sh[128];
    int t = threadIdx.x;
    int v = (t < nb) ? bsum[t] : 0;
    sh[t] = v;
    __syncthreads();
    for (int off = 1; off < 128; off <<= 1) {
        int a = (t >= off) ? sh[t - off] : 0;
        __syncthreads();
        sh[t] += a;
        __syncthreads();
    }
    if (t < nb) bsum[t] = sh[t] - v;   // exclusive block offsets
}

__global__ void scan3_kernel(const int* __restrict__ tmp, const int* __restrict__ cnt,
                             const int* __restrict__ bsum, int* __restrict__ rp, int n) {
    int i = blockIdx.x * 1024 + threadIdx.x;
    if (i < n) {
        int base = bsum[blockIdx.x];
        rp[i] = base + tmp[i] - cnt[i];          // exclusive
        if (i == n - 1) rp[n] = base + tmp[i];   // total
    }
}

__global__ void fill_kernel(const int* __restrict__ src, const int* __restrict__ dst,
                            const int* __restrict__ rp, int* __restrict__ fill,
                            int* __restrict__ csrc, int n) {
    int e = blockIdx.x * blockDim.x + threadIdx.x;
    if (e < n) {
        int d = dst[e];
        int pos = rp[d] + atomicAdd(&fill[d], 1);
        csrc[pos] = src[e];
    }
}

// ---------------- W1 -> W1t bf16 [256 cols][512 k] (K padded 500->512 with zeros) ----------------
__global__ void convW1t_kernel(const float* __restrict__ W1, unsigned short* __restrict__ W1t) {
    int i = blockIdx.x * blockDim.x + threadIdx.x;
    if (i < 256 * 512) {
        int n = i >> 9, k = i & 511;
        W1t[i] = (k < 500) ? f2bf(W1[(size_t)k * 256 + n]) : (unsigned short)0;
    }
}

// ---------------- GEMM1 (MFMA bf16): h1b = bf16(x @ W1), M=100000 K=500(512) N=256 ----------------
// Block: 128x256 output, 8 waves (2x4 of 64x64), BK=64, single-buffered LDS,
// XOR-swizzled LDS (slot ^ (row&7)) -> conflict-free ds_read_b128 / ds_write_b128.
#define G1_BM 128
#define G1_BN 256
#define G1_BK 64

__launch_bounds__(512)
__global__ void gemm1_mfma(const float* __restrict__ A,            // x [M][500] fp32
                           const unsigned short* __restrict__ Bt,  // W1t [256][512] bf16
                           unsigned short* __restrict__ C,         // h1b [M][256] bf16
                           int M) {
    __shared__ char lds[(G1_BM + G1_BN) * G1_BK * 2];  // As 16KB + Bs 32KB
    char* As = lds;
    char* Bs = lds + G1_BM * G1_BK * 2;
    const int t = threadIdx.x;
    const int l = t & 63;
    const int w = t >> 6;
    const int wr = w >> 2;   // 0..1
    const int wc = w & 3;    // 0..3
    const int bm = blockIdx.x * G1_BM;

    f32x4 acc[4][4] = {};

    for (int k0 = 0; k0 < 512; k0 += G1_BK) {
        // stage A: 1024 x 16B chunks; convert fp32->bf16 in flight; swizzled ds_write_b128
#pragma unroll
        for (int j = 0; j < 2; j++) {
            int c = j * 512 + t;
            int row = c >> 3, slot = c & 7;
            int R = bm + row;
            int kbase = k0 + slot * 8;
            float f[8];
            if (R < M && kbase + 8 <= 500) {
                float4 u0 = *(const float4*)(A + (size_t)R * 500 + kbase);
                float4 u1 = *(const float4*)(A + (size_t)R * 500 + kbase + 4);
                f[0] = u0.x; f[1] = u0.y; f[2] = u0.z; f[3] = u0.w;
                f[4] = u1.x; f[5] = u1.y; f[6] = u1.z; f[7] = u1.w;
            } else {
#pragma unroll
                for (int i = 0; i < 8; i++) {
                    int k = kbase + i;
                    f[i] = (R < M && k < 500) ? A[(size_t)R * 500 + k] : 0.f;
                }
            }
            union { uint4 u; unsigned short s[8]; } pk;
#pragma unroll
            for (int i = 0; i < 8; i++) pk.s[i] = f2bf(f[i]);
            *(uint4*)(As + row * 128 + ((slot ^ (row & 7)) * 16)) = pk.u;
        }
        // stage B: 2048 x 16B chunks (already bf16, already transposed)
#pragma unroll
        for (int j = 0; j < 4; j++) {
            int c = j * 512 + t;
            int col = c >> 3, slot = c & 7;
            uint4 v = *(const uint4*)(Bt + (size_t)col * 512 + k0 + slot * 8);
            *(uint4*)(Bs + col * 128 + ((slot ^ (col & 7)) * 16)) = v;
        }
        __syncthreads();
#pragma unroll
        for (int kk = 0; kk < 2; kk++) {
            bf16x8 af[4], bg[4];
#pragma unroll
            for (int m = 0; m < 4; m++) {
                int row = wr * 64 + m * 16 + (l & 15);
                int slot = kk * 4 + (l >> 4);
                af[m] = *(const bf16x8*)(As + row * 128 + ((slot ^ (row & 7)) * 16));
            }
#pragma unroll
            for (int n = 0; n < 4; n++) {
                int col = wc * 64 + n * 16 + (l & 15);
                int slot = kk * 4 + (l >> 4);
                bg[n] = *(const bf16x8*)(Bs + col * 128 + ((slot ^ (col & 7)) * 16));
            }
#pragma unroll
            for (int m = 0; m < 4; m++)
#pragma unroll
                for (int n = 0; n < 4; n++)
                    acc[m][n] = __builtin_amdgcn_mfma_f32_16x16x32_bf16(af[m], bg[n], acc[m][n], 0, 0, 0);
        }
        __syncthreads();
    }
    // epilogue: C/D layout col=lane&15, row=(lane>>4)*4+j  [m89-verified]
#pragma unroll
    for (int m = 0; m < 4; m++) {
#pragma unroll
        for (int j = 0; j < 4; j++) {
            int row = bm + wr * 64 + m * 16 + (l >> 4) * 4 + j;
            if (row < M) {
#pragma unroll
                for (int n = 0; n < 4; n++) {
                    int col = wc * 64 + n * 16 + (l & 15);
                    C[(size_t)row * 256 + col] = f2bf(acc[m][n][j]);
                }
            }
        }
    }
}

// ---------------- aggregation layer 1: gather bf16 h1 rows, fp32 accum, +bias, relu ----------------
__global__ void agg1_kernel(const unsigned short* __restrict__ h, const float* __restrict__ dinv,
                            const int* __restrict__ rp, const int* __restrict__ csrc,
                            const float* __restrict__ bias, float* __restrict__ out, int n) {
    int wave = (blockIdx.x * blockDim.x + threadIdx.x) >> 6;
    int lane = threadIdx.x & 63;
    if (wave >= n) return;
    int v = wave;
    float dv = dinv[v];
    ushort4 sv = ((const ushort4*)(h + (size_t)v * 256))[lane];
    float a0 = bf2f(sv.x) * dv, a1 = bf2f(sv.y) * dv, a2 = bf2f(sv.z) * dv, a3 = bf2f(sv.w) * dv;
    int b0 = rp[v], b1e = rp[v + 1];
    for (int i = b0; i < b1e; i++) {
        int s = csrc[i];
        float ds = dinv[s];
        ushort4 hs = ((const ushort4*)(h + (size_t)s * 256))[lane];
        a0 += bf2f(hs.x) * ds; a1 += bf2f(hs.y) * ds;
        a2 += bf2f(hs.z) * ds; a3 += bf2f(hs.w) * ds;
    }
    float4 bb = ((const float4*)bias)[lane];
    float4 o;
    o.x = fmaxf(a0 * dv + bb.x, 0.f);
    o.y = fmaxf(a1 * dv + bb.y, 0.f);
    o.z = fmaxf(a2 * dv + bb.z, 0.f);
    o.w = fmaxf(a3 * dv + bb.w, 0.f);
    ((float4*)(out + (size_t)v * 256))[lane] = o;
}

// ---------------- GEMM2: h2 = h1a @ W2 (K=256 -> N=64), W2 fully in LDS ----------------
__global__ void gemm2_kernel(const float* __restrict__ X, const float* __restrict__ W2,
                             float* __restrict__ Y, int n) {
    extern __shared__ float smem[];
    float* W2s = smem;             // 256*64
    float* rows = smem + 256 * 64; // 4 * 260
    int t = threadIdx.x;
    for (int i = t; i < 256 * 64; i += 256) W2s[i] = W2[i];
    __syncthreads();
    int wv = t >> 6, lane = t & 63;
    float* myrow = rows + wv * 260;
    for (int v = blockIdx.x * 4 + wv; v < n; v += gridDim.x * 4) {
        float4 rv = ((const float4*)(X + (size_t)v * 256))[lane];
        ((float4*)myrow)[lane] = rv;
        float acc = 0.f;
        const float4* r4 = (const float4*)myrow;
#pragma unroll 8
        for (int k4 = 0; k4 < 64; k4++) {
            float4 rk = r4[k4];
            acc += rk.x * W2s[(k4 * 4 + 0) * 64 + lane];
            acc += rk.y * W2s[(k4 * 4 + 1) * 64 + lane];
            acc += rk.z * W2s[(k4 * 4 + 2) * 64 + lane];
            acc += rk.w * W2s[(k4 * 4 + 3) * 64 + lane];
        }
        Y[(size_t)v * 64 + lane] = acc;
    }
}

// ---------------- aggregation layer 2 (64 cols, wave per node) ----------------
__global__ void agg2_kernel(const float* __restrict__ h, const float* __restrict__ dinv,
                            const int* __restrict__ rp, const int* __restrict__ csrc,
                            const float* __restrict__ bias, float* __restrict__ out, int n) {
    int wave = (blockIdx.x * blockDim.x + threadIdx.x) >> 6;
    int lane = threadIdx.x & 63;
    if (wave >= n) return;
    int v = wave;
    float dv = dinv[v];
    float acc = h[(size_t)v * 64 + lane] * dv;
    int b0 = rp[v], b1e = rp[v + 1];
    for (int i = b0; i < b1e; i++) {
        int s = csrc[i];
        acc += h[(size_t)s * 64 + lane] * dinv[s];
    }
    out[(size_t)v * 64 + lane] = fmaxf(acc * dv + bias[lane], 0.f);
}

// ---------------- heads: p[v] = h@WW ; biases[v] = h@WB + bB ----------------
__global__ void heads_kernel(const float* __restrict__ h, const float* __restrict__ WW,
                             const float* __restrict__ WB, const float* __restrict__ bB,
                             float* __restrict__ p, float* __restrict__ outB, int n) {
    int wave = (blockIdx.x * blockDim.x + threadIdx.x) >> 6;
    int lane = threadIdx.x & 63;
    if (wave >= n) return;
    int v = wave;
    float hv = h[(size_t)v * 64 + lane];
    float pw = hv * WW[lane];
    float pb = hv * WB[lane];
#pragma unroll
    for (int off = 32; off >= 1; off >>= 1) {
        pw += __shfl_xor(pw, off);
        pb += __shfl_xor(pb, off);
    }
    if (lane == 0) {
        p[v] = pw;
        outB[v] = pb + bB[0];
    }
}

__global__ void weights_kernel(const int* __restrict__ src, const int* __restrict__ dst,
                               const float* __restrict__ p, const float* __restrict__ bW,
                               float* __restrict__ outW, int n) {
    int i = blockIdx.x * blockDim.x + threadIdx.x;
    if (i < n) {
        int e = 2 * i;
        outW[i] = 0.5f * (p[src[e]] + p[dst[e]]) + bW[0];
    }
}

// ---------------- launch ----------------

extern "C" void kernel_launch(void* const* d_in, const int* in_sizes, int n_in,
                              void* d_out, int out_size, void* d_ws, size_t ws_size,
                              hipStream_t stream) {
    const float* x  = (const float*)d_in[0];
    const int*   ei = (const int*)d_in[1];
    const int*   src = ei;
    const int*   dst = ei + NE;
    const float* W1 = (const float*)d_in[2];
    const float* b1 = (const float*)d_in[3];
    const float* W2 = (const float*)d_in[4];
    const float* b2 = (const float*)d_in[5];
    const float* WB = (const float*)d_in[6];
    const float* bB = (const float*)d_in[7];
    const float* WW = (const float*)d_in[8];
    const float* bW = (const float*)d_in[9];
    float* outW = (float*)d_out;          // 500000 weights
    float* outB = (float*)d_out + 500000; // 100000 biases

    char* ws = (char*)d_ws;
    unsigned short* h1b = (unsigned short*)(ws);               // [100000][256] bf16 = 51.2MB
    float* h1a = (float*)(ws + 51200000);                      // [100000][256] f32 = 102.4MB
    float* h2  = (float*)(ws);                                 // overlays dead h1b, 25.6MB
    float* h2a = (float*)(ws + 25600000);                      // 25.6MB
    float* p   = (float*)(ws + 153600000);                     // 400KB
    char* tail = ws + 155000000;
    float* dinv = (float*)(tail);                              // 400,000
    int*   rp   = (int*)(tail + 400000);                       // 400,064
    int*   cnt  = (int*)(tail + 800064);                       // 400,000
    int*   fill = (int*)(tail + 1200064);                      // 400,000
    int*   csrc = (int*)(tail + 1600064);                      // 4,000,000
    int*   tmp  = (int*)(tail + 5600064);                      // 400,000
    int*   bsum = (int*)(tail + 6000064);                      // 512
    unsigned short* W1t = (unsigned short*)(tail + 6000576);   // 262,144

    hipMemsetAsync(cnt, 0, 800000, stream);  // cnt + fill (contiguous)

    count_kernel<<<(NE + 255) / 256, 256, 0, stream>>>(dst, cnt, NE);
    dinv_kernel<<<(NN + 255) / 256, 256, 0, stream>>>(cnt, dinv, NN);
    int nblk = (NN + 1023) / 1024;  // 98
    scan1_kernel<<<nblk, 1024, 0, stream>>>(cnt, tmp, bsum, NN);
    scan2_kernel<<<1, 128, 0, stream>>>(bsum, nblk);
    scan3_kernel<<<nblk, 1024, 0, stream>>>(tmp, cnt, bsum, rp, NN);
    fill_kernel<<<(NE + 255) / 256, 256, 0, stream>>>(src, dst, rp, fill, csrc, NE);

    convW1t_kernel<<<(256 * 512 + 255) / 256, 256, 0, stream>>>(W1, W1t);
    gemm1_mfma<<<(NN + G1_BM - 1) / G1_BM, 512, 0, stream>>>(x, W1t, h1b, NN);
    agg1_kernel<<<(NN + 3) / 4, 256, 0, stream>>>(h1b, dinv, rp, csrc, b1, h1a, NN);

    size_t g2lds = (256 * 64 + 4 * 260) * sizeof(float);
    gemm2_kernel<<<512, 256, g2lds, stream>>>(h1a, W2, h2, NN);
    agg2_kernel<<<(NN + 3) / 4, 256, 0, stream>>>(h2, dinv, rp, csrc, b2, h2a, NN);

    heads_kernel<<<(NN + 3) / 4, 256, 0, stream>>>(h2a, WW, WB, bB, p, outB, NN);
    weights_kernel<<<(500000 + 255) / 256, 256, 0, stream>>>(src, dst, p, bW, outW, 500000);
}

// Round 6
// 699.003 us; speedup vs baseline: 2.2526x; 1.3432x over previous
//
#include <hip/hip_runtime.h>
#include <hip/hip_bf16.h>
#include <math.h>

#define NN 100000
#define NE 1000000

typedef __attribute__((ext_vector_type(8))) short bf16x8;
typedef __attribute__((ext_vector_type(4))) float f32x4;

__device__ __forceinline__ unsigned short f2bf(float f) {
    unsigned int u = __builtin_bit_cast(unsigned int, f);
    unsigned int r = (u + 0x7fff + ((u >> 16) & 1)) >> 16;   // RNE
    return (unsigned short)r;
}
__device__ __forceinline__ float bf2f(unsigned short s) {
    unsigned int u = ((unsigned int)s) << 16;
    return __builtin_bit_cast(float, u);
}

// ---------------- degree / CSR build ----------------

__global__ void count_kernel(const int* __restrict__ dst, int* __restrict__ cnt, int n) {
    int e = blockIdx.x * blockDim.x + threadIdx.x;
    if (e < n) atomicAdd(&cnt[dst[e]], 1);
}

__global__ void dinv_kernel(const int* __restrict__ cnt, float* __restrict__ dinv, int n) {
    int v = blockIdx.x * blockDim.x + threadIdx.x;
    if (v < n) dinv[v] = 1.0f / sqrtf((float)cnt[v] + 1.0f);  // +1 self-loop
}

// parallel scan: per-chunk inclusive (scan1) -> chunk sums exclusive (scan2) -> combine (scan3)
__global__ void scan1_kernel(const int* __restrict__ cnt, int* __restrict__ tmp,
                             int* __restrict__ bsum, int n) {
    __shared__ int sh[1024];
    int t = threadIdx.x;
    int i = blockIdx.x * 1024 + t;
    int v = (i < n) ? cnt[i] : 0;
    sh[t] = v;
    __syncthreads();
    for (int off = 1; off < 1024; off <<= 1) {
        int a = (t >= off) ? sh[t - off] : 0;
        __syncthreads();
        sh[t] += a;
        __syncthreads();
    }
    if (i < n) tmp[i] = sh[t];
    if (t == 1023) bsum[blockIdx.x] = sh[t];
}

__global__ void scan2_kernel(int* __restrict__ bsum, int nb) {
    __shared__ int sh[128];
    int t = threadIdx.x;
    int v = (t < nb) ? bsum[t] : 0;
    sh[t] = v;
    __syncthreads();
    for (int off = 1; off < 128; off <<= 1) {
        int a = (t >= off) ? sh[t - off] : 0;
        __syncthreads();
        sh[t] += a;
        __syncthreads();
    }
    if (t < nb) bsum[t] = sh[t] - v;   // exclusive block offsets
}

__global__ void scan3_kernel(const int* __restrict__ tmp, const int* __restrict__ cnt,
                             const int* __restrict__ bsum, int* __restrict__ rp, int n) {
    int i = blockIdx.x * 1024 + threadIdx.x;
    if (i < n) {
        int base = bsum[blockIdx.x];
        rp[i] = base + tmp[i] - cnt[i];          // exclusive
        if (i == n - 1) rp[n] = base + tmp[i];   // total
    }
}

__global__ void fill_kernel(const int* __restrict__ src, const int* __restrict__ dst,
                            const int* __restrict__ rp, int* __restrict__ fill,
                            int* __restrict__ csrc, int n) {
    int e = blockIdx.x * blockDim.x + threadIdx.x;
    if (e < n) {
        int d = dst[e];
        int pos = rp[d] + atomicAdd(&fill[d], 1);
        csrc[pos] = src[e];
    }
}

// ---------------- W1 -> W1t bf16 [256 cols][512 k] (K padded 500->512 with zeros) ----------------
__global__ void convW1t_kernel(const float* __restrict__ W1, unsigned short* __restrict__ W1t) {
    int i = blockIdx.x * blockDim.x + threadIdx.x;
    if (i < 256 * 512) {
        int n = i >> 9, k = i & 511;
        W1t[i] = (k < 500) ? f2bf(W1[(size_t)k * 256 + n]) : (unsigned short)0;
    }
}

// ---------------- W2 -> W2t bf16 [64 cols][256 k] ----------------
__global__ void convW2t_kernel(const float* __restrict__ W2, unsigned short* __restrict__ W2t) {
    int i = blockIdx.x * blockDim.x + threadIdx.x;
    if (i < 64 * 256) {
        int n = i >> 8, k = i & 255;
        W2t[i] = f2bf(W2[(size_t)k * 64 + n]);
    }
}

// ---------------- GEMM1 (MFMA bf16): h1b = bf16(x @ W1), M=100000 K=500(512) N=256 ----------------
// Block: 128x256 output, 8 waves (2x4 of 64x64), BK=64, single-buffered LDS,
// XOR-swizzled LDS (slot ^ (row&7)) -> conflict-free ds_read_b128 / ds_write_b128.
#define G1_BM 128
#define G1_BN 256
#define G1_BK 64

__launch_bounds__(512)
__global__ void gemm1_mfma(const float* __restrict__ A,            // x [M][500] fp32
                           const unsigned short* __restrict__ Bt,  // W1t [256][512] bf16
                           unsigned short* __restrict__ C,         // h1b [M][256] bf16
                           int M) {
    __shared__ char lds[(G1_BM + G1_BN) * G1_BK * 2];  // As 16KB + Bs 32KB
    char* As = lds;
    char* Bs = lds + G1_BM * G1_BK * 2;
    const int t = threadIdx.x;
    const int l = t & 63;
    const int w = t >> 6;
    const int wr = w >> 2;   // 0..1
    const int wc = w & 3;    // 0..3
    const int bm = blockIdx.x * G1_BM;

    f32x4 acc[4][4] = {};

    for (int k0 = 0; k0 < 512; k0 += G1_BK) {
        // stage A: 1024 x 16B chunks; convert fp32->bf16 in flight; swizzled ds_write_b128
#pragma unroll
        for (int j = 0; j < 2; j++) {
            int c = j * 512 + t;
            int row = c >> 3, slot = c & 7;
            int R = bm + row;
            int kbase = k0 + slot * 8;
            float f[8];
            if (R < M && kbase + 8 <= 500) {
                float4 u0 = *(const float4*)(A + (size_t)R * 500 + kbase);
                float4 u1 = *(const float4*)(A + (size_t)R * 500 + kbase + 4);
                f[0] = u0.x; f[1] = u0.y; f[2] = u0.z; f[3] = u0.w;
                f[4] = u1.x; f[5] = u1.y; f[6] = u1.z; f[7] = u1.w;
            } else {
#pragma unroll
                for (int i = 0; i < 8; i++) {
                    int k = kbase + i;
                    f[i] = (R < M && k < 500) ? A[(size_t)R * 500 + k] : 0.f;
                }
            }
            union { uint4 u; unsigned short s[8]; } pk;
#pragma unroll
            for (int i = 0; i < 8; i++) pk.s[i] = f2bf(f[i]);
            *(uint4*)(As + row * 128 + ((slot ^ (row & 7)) * 16)) = pk.u;
        }
        // stage B: 2048 x 16B chunks (already bf16, already transposed)
#pragma unroll
        for (int j = 0; j < 4; j++) {
            int c = j * 512 + t;
            int col = c >> 3, slot = c & 7;
            uint4 v = *(const uint4*)(Bt + (size_t)col * 512 + k0 + slot * 8);
            *(uint4*)(Bs + col * 128 + ((slot ^ (col & 7)) * 16)) = v;
        }
        __syncthreads();
#pragma unroll
        for (int kk = 0; kk < 2; kk++) {
            bf16x8 af[4], bg[4];
#pragma unroll
            for (int m = 0; m < 4; m++) {
                int row = wr * 64 + m * 16 + (l & 15);
                int slot = kk * 4 + (l >> 4);
                af[m] = *(const bf16x8*)(As + row * 128 + ((slot ^ (row & 7)) * 16));
            }
#pragma unroll
            for (int n = 0; n < 4; n++) {
                int col = wc * 64 + n * 16 + (l & 15);
                int slot = kk * 4 + (l >> 4);
                bg[n] = *(const bf16x8*)(Bs + col * 128 + ((slot ^ (col & 7)) * 16));
            }
#pragma unroll
            for (int m = 0; m < 4; m++)
#pragma unroll
                for (int n = 0; n < 4; n++)
                    acc[m][n] = __builtin_amdgcn_mfma_f32_16x16x32_bf16(af[m], bg[n], acc[m][n], 0, 0, 0);
        }
        __syncthreads();
    }
    // epilogue: C/D layout col=lane&15, row=(lane>>4)*4+j  [m89-verified]
#pragma unroll
    for (int m = 0; m < 4; m++) {
#pragma unroll
        for (int j = 0; j < 4; j++) {
            int row = bm + wr * 64 + m * 16 + (l >> 4) * 4 + j;
            if (row < M) {
#pragma unroll
                for (int n = 0; n < 4; n++) {
                    int col = wc * 64 + n * 16 + (l & 15);
                    C[(size_t)row * 256 + col] = f2bf(acc[m][n][j]);
                }
            }
        }
    }
}

// ---------------- aggregation layer 1: gather bf16 h1 rows, fp32 accum, +bias, relu -> bf16 ----------------
__global__ void agg1_kernel(const unsigned short* __restrict__ h, const float* __restrict__ dinv,
                            const int* __restrict__ rp, const int* __restrict__ csrc,
                            const float* __restrict__ bias, unsigned short* __restrict__ out, int n) {
    int wave = (blockIdx.x * blockDim.x + threadIdx.x) >> 6;
    int lane = threadIdx.x & 63;
    if (wave >= n) return;
    int v = wave;
    float dv = dinv[v];
    ushort4 sv = ((const ushort4*)(h + (size_t)v * 256))[lane];
    float a0 = bf2f(sv.x) * dv, a1 = bf2f(sv.y) * dv, a2 = bf2f(sv.z) * dv, a3 = bf2f(sv.w) * dv;
    int b0 = rp[v], b1e = rp[v + 1];
    for (int i = b0; i < b1e; i++) {
        int s = csrc[i];
        float ds = dinv[s];
        ushort4 hs = ((const ushort4*)(h + (size_t)s * 256))[lane];
        a0 += bf2f(hs.x) * ds; a1 += bf2f(hs.y) * ds;
        a2 += bf2f(hs.z) * ds; a3 += bf2f(hs.w) * ds;
    }
    float4 bb = ((const float4*)bias)[lane];
    ushort4 ov;
    ov.x = f2bf(fmaxf(a0 * dv + bb.x, 0.f));
    ov.y = f2bf(fmaxf(a1 * dv + bb.y, 0.f));
    ov.z = f2bf(fmaxf(a2 * dv + bb.z, 0.f));
    ov.w = f2bf(fmaxf(a3 * dv + bb.w, 0.f));
    ((ushort4*)(out + (size_t)v * 256))[lane] = ov;
}

// ---------------- GEMM2 (MFMA bf16): h2 = h1a @ W2, M=100000 K=256 N=64 ----------------
// Block: 256x64 output, 8 waves (wave tile 32x64, acc[2][4]), BK=64, same swizzle as GEMM1.
#define G2_BM 256
#define G2_BN 64
#define G2_BK 64

__launch_bounds__(512)
__global__ void gemm2_mfma(const unsigned short* __restrict__ A,   // h1a bf16 [M][256]
                           const unsigned short* __restrict__ Bt,  // W2t [64][256] bf16
                           float* __restrict__ C,                  // h2 [M][64] fp32
                           int M) {
    __shared__ char lds[(G2_BM + G2_BN) * G2_BK * 2];  // As 32KB + Bs 8KB
    char* As = lds;
    char* Bs = lds + G2_BM * G2_BK * 2;
    const int t = threadIdx.x;
    const int l = t & 63;
    const int w = t >> 6;                 // wave row 0..7
    const int bm = blockIdx.x * G2_BM;

    f32x4 acc[2][4] = {};

    for (int k0 = 0; k0 < 256; k0 += G2_BK) {
        // stage A: 2048 x 16B chunks (bf16 source), 4 per thread
#pragma unroll
        for (int j = 0; j < 4; j++) {
            int c = j * 512 + t;
            int row = c >> 3, slot = c & 7;
            int R = bm + row;
            uint4 v = {0, 0, 0, 0};
            if (R < M) v = *(const uint4*)(A + (size_t)R * 256 + k0 + slot * 8);
            *(uint4*)(As + row * 128 + ((slot ^ (row & 7)) * 16)) = v;
        }
        // stage B: 512 x 16B chunks, 1 per thread
        {
            int col = t >> 3, slot = t & 7;
            uint4 v = *(const uint4*)(Bt + (size_t)col * 256 + k0 + slot * 8);
            *(uint4*)(Bs + col * 128 + ((slot ^ (col & 7)) * 16)) = v;
        }
        __syncthreads();
#pragma unroll
        for (int kk = 0; kk < 2; kk++) {
            bf16x8 af[2], bg[4];
#pragma unroll
            for (int m = 0; m < 2; m++) {
                int row = w * 32 + m * 16 + (l & 15);
                int slot = kk * 4 + (l >> 4);
                af[m] = *(const bf16x8*)(As + row * 128 + ((slot ^ (row & 7)) * 16));
            }
#pragma unroll
            for (int n = 0; n < 4; n++) {
                int col = n * 16 + (l & 15);
                int slot = kk * 4 + (l >> 4);
                bg[n] = *(const bf16x8*)(Bs + col * 128 + ((slot ^ (col & 7)) * 16));
            }
#pragma unroll
            for (int m = 0; m < 2; m++)
#pragma unroll
                for (int n = 0; n < 4; n++)
                    acc[m][n] = __builtin_amdgcn_mfma_f32_16x16x32_bf16(af[m], bg[n], acc[m][n], 0, 0, 0);
        }
        __syncthreads();
    }
#pragma unroll
    for (int m = 0; m < 2; m++) {
#pragma unroll
        for (int j = 0; j < 4; j++) {
            int row = bm + w * 32 + m * 16 + (l >> 4) * 4 + j;
            if (row < M) {
#pragma unroll
                for (int n = 0; n < 4; n++) {
                    int col = n * 16 + (l & 15);
                    C[(size_t)row * 64 + col] = acc[m][n][j];
                }
            }
        }
    }
}

// ---------------- aggregation layer 2 (64 cols, wave per node) ----------------
__global__ void agg2_kernel(const float* __restrict__ h, const float* __restrict__ dinv,
                            const int* __restrict__ rp, const int* __restrict__ csrc,
                            const float* __restrict__ bias, float* __restrict__ out, int n) {
    int wave = (blockIdx.x * blockDim.x + threadIdx.x) >> 6;
    int lane = threadIdx.x & 63;
    if (wave >= n) return;
    int v = wave;
    float dv = dinv[v];
    float acc = h[(size_t)v * 64 + lane] * dv;
    int b0 = rp[v], b1e = rp[v + 1];
    for (int i = b0; i < b1e; i++) {
        int s = csrc[i];
        acc += h[(size_t)s * 64 + lane] * dinv[s];
    }
    out[(size_t)v * 64 + lane] = fmaxf(acc * dv + bias[lane], 0.f);
}

// ---------------- heads: p[v] = h@WW ; biases[v] = h@WB + bB ----------------
__global__ void heads_kernel(const float* __restrict__ h, const float* __restrict__ WW,
                             const float* __restrict__ WB, const float* __restrict__ bB,
                             float* __restrict__ p, float* __restrict__ outB, int n) {
    int wave = (blockIdx.x * blockDim.x + threadIdx.x) >> 6;
    int lane = threadIdx.x & 63;
    if (wave >= n) return;
    int v = wave;
    float hv = h[(size_t)v * 64 + lane];
    float pw = hv * WW[lane];
    float pb = hv * WB[lane];
#pragma unroll
    for (int off = 32; off >= 1; off >>= 1) {
        pw += __shfl_xor(pw, off);
        pb += __shfl_xor(pb, off);
    }
    if (lane == 0) {
        p[v] = pw;
        outB[v] = pb + bB[0];
    }
}

__global__ void weights_kernel(const int* __restrict__ src, const int* __restrict__ dst,
                               const float* __restrict__ p, const float* __restrict__ bW,
                               float* __restrict__ outW, int n) {
    int i = blockIdx.x * blockDim.x + threadIdx.x;
    if (i < n) {
        int e = 2 * i;
        outW[i] = 0.5f * (p[src[e]] + p[dst[e]]) + bW[0];
    }
}

// ---------------- launch ----------------

extern "C" void kernel_launch(void* const* d_in, const int* in_sizes, int n_in,
                              void* d_out, int out_size, void* d_ws, size_t ws_size,
                              hipStream_t stream) {
    const float* x  = (const float*)d_in[0];
    const int*   ei = (const int*)d_in[1];
    const int*   src = ei;
    const int*   dst = ei + NE;
    const float* W1 = (const float*)d_in[2];
    const float* b1 = (const float*)d_in[3];
    const float* W2 = (const float*)d_in[4];
    const float* b2 = (const float*)d_in[5];
    const float* WB = (const float*)d_in[6];
    const float* bB = (const float*)d_in[7];
    const float* WW = (const float*)d_in[8];
    const float* bW = (const float*)d_in[9];
    float* outW = (float*)d_out;          // 500000 weights
    float* outB = (float*)d_out + 500000; // 100000 biases

    char* ws = (char*)d_ws;
    unsigned short* h1b = (unsigned short*)(ws);               // [100000][256] bf16 = 51.2MB
    unsigned short* h1a = (unsigned short*)(ws + 51200000);    // [100000][256] bf16 = 51.2MB
    float* h2  = (float*)(ws);                                 // overlays dead h1b, 25.6MB
    float* h2a = (float*)(ws + 25600000);                      // 25.6MB
    float* p   = (float*)(ws + 153600000);                     // 400KB
    char* tail = ws + 155000000;
    float* dinv = (float*)(tail);                              // 400,000
    int*   rp   = (int*)(tail + 400000);                       // 400,064
    int*   cnt  = (int*)(tail + 800064);                       // 400,000
    int*   fill = (int*)(tail + 1200064);                      // 400,000
    int*   csrc = (int*)(tail + 1600064);                      // 4,000,000
    int*   tmp  = (int*)(tail + 5600064);                      // 400,000
    int*   bsum = (int*)(tail + 6000064);                      // 512
    unsigned short* W1t = (unsigned short*)(tail + 6000576);   // 262,144 bf16 = 524,288 B
    unsigned short* W2t = (unsigned short*)(tail + 6524864);   // 16,384 bf16 = 32,768 B

    hipMemsetAsync(cnt, 0, 800000, stream);  // cnt + fill (contiguous)

    count_kernel<<<(NE + 255) / 256, 256, 0, stream>>>(dst, cnt, NE);
    dinv_kernel<<<(NN + 255) / 256, 256, 0, stream>>>(cnt, dinv, NN);
    int nblk = (NN + 1023) / 1024;  // 98
    scan1_kernel<<<nblk, 1024, 0, stream>>>(cnt, tmp, bsum, NN);
    scan2_kernel<<<1, 128, 0, stream>>>(bsum, nblk);
    scan3_kernel<<<nblk, 1024, 0, stream>>>(tmp, cnt, bsum, rp, NN);
    fill_kernel<<<(NE + 255) / 256, 256, 0, stream>>>(src, dst, rp, fill, csrc, NE);

    convW1t_kernel<<<(256 * 512 + 255) / 256, 256, 0, stream>>>(W1, W1t);
    convW2t_kernel<<<(64 * 256 + 255) / 256, 256, 0, stream>>>(W2, W2t);
    gemm1_mfma<<<(NN + G1_BM - 1) / G1_BM, 512, 0, stream>>>(x, W1t, h1b, NN);
    agg1_kernel<<<(NN + 3) / 4, 256, 0, stream>>>(h1b, dinv, rp, csrc, b1, h1a, NN);

    gemm2_mfma<<<(NN + G2_BM - 1) / G2_BM, 512, 0, stream>>>(h1a, W2t, h2, NN);
    agg2_kernel<<<(NN + 3) / 4, 256, 0, stream>>>(h2, dinv, rp, csrc, b2, h2a, NN);

    heads_kernel<<<(NN + 3) / 4, 256, 0, stream>>>(h2a, WW, WB, bB, p, outB, NN);
    weights_kernel<<<(500000 + 255) / 256, 256, 0, stream>>>(src, dst, p, bW, outW, 500000);
}

// Round 7
// 661.824 us; speedup vs baseline: 2.3792x; 1.0562x over previous
//
#include <hip/hip_runtime.h>
#include <hip/hip_bf16.h>
#include <math.h>

#define NN 100000
#define NE 1000000

typedef __attribute__((ext_vector_type(8))) short bf16x8;
typedef __attribute__((ext_vector_type(4))) float f32x4;

__device__ __forceinline__ unsigned short f2bf(float f) {
    unsigned int u = __builtin_bit_cast(unsigned int, f);
    unsigned int r = (u + 0x7fff + ((u >> 16) & 1)) >> 16;   // RNE
    return (unsigned short)r;
}
__device__ __forceinline__ float bf2f(unsigned short s) {
    unsigned int u = ((unsigned int)s) << 16;
    return __builtin_bit_cast(float, u);
}

// ---------------- degree / CSR build ----------------

__global__ void count_kernel(const int* __restrict__ dst, int* __restrict__ cnt, int n) {
    int e = blockIdx.x * blockDim.x + threadIdx.x;
    if (e < n) atomicAdd(&cnt[dst[e]], 1);
}

__global__ void dinv_kernel(const int* __restrict__ cnt, float* __restrict__ dinv, int n) {
    int v = blockIdx.x * blockDim.x + threadIdx.x;
    if (v < n) dinv[v] = 1.0f / sqrtf((float)cnt[v] + 1.0f);  // +1 self-loop
}

// parallel scan: per-chunk inclusive (scan1) -> chunk sums exclusive (scan2) -> combine (scan3)
__global__ void scan1_kernel(const int* __restrict__ cnt, int* __restrict__ tmp,
                             int* __restrict__ bsum, int n) {
    __shared__ int sh[1024];
    int t = threadIdx.x;
    int i = blockIdx.x * 1024 + t;
    int v = (i < n) ? cnt[i] : 0;
    sh[t] = v;
    __syncthreads();
    for (int off = 1; off < 1024; off <<= 1) {
        int a = (t >= off) ? sh[t - off] : 0;
        __syncthreads();
        sh[t] += a;
        __syncthreads();
    }
    if (i < n) tmp[i] = sh[t];
    if (t == 1023) bsum[blockIdx.x] = sh[t];
}

__global__ void scan2_kernel(int* __restrict__ bsum, int nb) {
    __shared__ int sh[128];
    int t = threadIdx.x;
    int v = (t < nb) ? bsum[t] : 0;
    sh[t] = v;
    __syncthreads();
    for (int off = 1; off < 128; off <<= 1) {
        int a = (t >= off) ? sh[t - off] : 0;
        __syncthreads();
        sh[t] += a;
        __syncthreads();
    }
    if (t < nb) bsum[t] = sh[t] - v;   // exclusive block offsets
}

__global__ void scan3_kernel(const int* __restrict__ tmp, const int* __restrict__ cnt,
                             const int* __restrict__ bsum, int* __restrict__ rp, int n) {
    int i = blockIdx.x * 1024 + threadIdx.x;
    if (i < n) {
        int base = bsum[blockIdx.x];
        rp[i] = base + tmp[i] - cnt[i];          // exclusive
        if (i == n - 1) rp[n] = base + tmp[i];   // total
    }
}

__global__ void fill_kernel(const int* __restrict__ src, const int* __restrict__ dst,
                            const int* __restrict__ rp, int* __restrict__ fill,
                            int* __restrict__ csrc, int n) {
    int e = blockIdx.x * blockDim.x + threadIdx.x;
    if (e < n) {
        int d = dst[e];
        int pos = rp[d] + atomicAdd(&fill[d], 1);
        csrc[pos] = src[e];
    }
}

// ---------------- W1 -> W1t bf16 [256 cols][512 k] (K padded 500->512 with zeros) ----------------
__global__ void convW1t_kernel(const float* __restrict__ W1, unsigned short* __restrict__ W1t) {
    int i = blockIdx.x * blockDim.x + threadIdx.x;
    if (i < 256 * 512) {
        int n = i >> 9, k = i & 511;
        W1t[i] = (k < 500) ? f2bf(W1[(size_t)k * 256 + n]) : (unsigned short)0;
    }
}

// ---------------- W2 -> W2t bf16 [64 cols][256 k] ----------------
__global__ void convW2t_kernel(const float* __restrict__ W2, unsigned short* __restrict__ W2t) {
    int i = blockIdx.x * blockDim.x + threadIdx.x;
    if (i < 64 * 256) {
        int n = i >> 8, k = i & 255;
        W2t[i] = f2bf(W2[(size_t)k * 64 + n]);
    }
}

// ---------------- GEMM1 (MFMA bf16, 2-phase pipelined): h1b = bf16(x @ W1) ----------------
// Block: 128x256 output, 8 waves (2x4 of 64x64), BK=64. T3-minimal pipeline:
// issue next K-tile global loads to regs BEFORE MFMA phase; LDS write after read-barrier.
#define G1_BM 128
#define G1_BN 256
#define G1_BK 64

__device__ __forceinline__ void g1_loadA(const float* __restrict__ A, int bm, int M, int t,
                                         int k0, float (&fr)[2][8]) {
#pragma unroll
    for (int j = 0; j < 2; j++) {
        int c = j * 512 + t;
        int row = c >> 3, slot = c & 7;
        int R = bm + row;
        int kbase = k0 + slot * 8;
        if (R < M && kbase + 8 <= 500) {
            float4 u0 = *(const float4*)(A + (size_t)R * 500 + kbase);
            float4 u1 = *(const float4*)(A + (size_t)R * 500 + kbase + 4);
            fr[j][0] = u0.x; fr[j][1] = u0.y; fr[j][2] = u0.z; fr[j][3] = u0.w;
            fr[j][4] = u1.x; fr[j][5] = u1.y; fr[j][6] = u1.z; fr[j][7] = u1.w;
        } else {
#pragma unroll
            for (int i = 0; i < 8; i++) {
                int k = kbase + i;
                fr[j][i] = (R < M && k < 500) ? A[(size_t)R * 500 + k] : 0.f;
            }
        }
    }
}

__device__ __forceinline__ void g1_loadB(const unsigned short* __restrict__ Bt, int t,
                                         int k0, uint4 (&vb)[4]) {
#pragma unroll
    for (int j = 0; j < 4; j++) {
        int c = j * 512 + t;
        int col = c >> 3, slot = c & 7;
        vb[j] = *(const uint4*)(Bt + (size_t)col * 512 + k0 + slot * 8);
    }
}

__device__ __forceinline__ void g1_write(char* As, char* Bs, int t,
                                         const float (&fr)[2][8], const uint4 (&vb)[4]) {
#pragma unroll
    for (int j = 0; j < 2; j++) {
        int c = j * 512 + t;
        int row = c >> 3, slot = c & 7;
        union { uint4 u; unsigned short s[8]; } pk;
#pragma unroll
        for (int i = 0; i < 8; i++) pk.s[i] = f2bf(fr[j][i]);
        *(uint4*)(As + row * 128 + ((slot ^ (row & 7)) * 16)) = pk.u;
    }
#pragma unroll
    for (int j = 0; j < 4; j++) {
        int c = j * 512 + t;
        int col = c >> 3, slot = c & 7;
        *(uint4*)(Bs + col * 128 + ((slot ^ (col & 7)) * 16)) = vb[j];
    }
}

__launch_bounds__(512)
__global__ void gemm1_mfma(const float* __restrict__ A,            // x [M][500] fp32
                           const unsigned short* __restrict__ Bt,  // W1t [256][512] bf16
                           unsigned short* __restrict__ C,         // h1b [M][256] bf16
                           int M) {
    __shared__ char lds[(G1_BM + G1_BN) * G1_BK * 2];  // As 16KB + Bs 32KB
    char* As = lds;
    char* Bs = lds + G1_BM * G1_BK * 2;
    const int t = threadIdx.x;
    const int l = t & 63;
    const int w = t >> 6;
    const int wr = w >> 2;   // 0..1
    const int wc = w & 3;    // 0..3
    const int bm = blockIdx.x * G1_BM;

    f32x4 acc[4][4] = {};
    float fr[2][8];
    uint4 vb[4];

    // prologue: stage tile 0
    g1_loadA(A, bm, M, t, 0, fr);
    g1_loadB(Bt, t, 0, vb);
    g1_write(As, Bs, t, fr, vb);
    __syncthreads();

    for (int k0 = 0; k0 < 512; k0 += G1_BK) {
        int kn = k0 + G1_BK;
        if (kn < 512) {          // issue next-tile loads (in flight across MFMA phase)
            g1_loadA(A, bm, M, t, kn, fr);
            g1_loadB(Bt, t, kn, vb);
        }
#pragma unroll
        for (int kk = 0; kk < 2; kk++) {
            bf16x8 af[4], bg[4];
#pragma unroll
            for (int m = 0; m < 4; m++) {
                int row = wr * 64 + m * 16 + (l & 15);
                int slot = kk * 4 + (l >> 4);
                af[m] = *(const bf16x8*)(As + row * 128 + ((slot ^ (row & 7)) * 16));
            }
#pragma unroll
            for (int n = 0; n < 4; n++) {
                int col = wc * 64 + n * 16 + (l & 15);
                int slot = kk * 4 + (l >> 4);
                bg[n] = *(const bf16x8*)(Bs + col * 128 + ((slot ^ (col & 7)) * 16));
            }
#pragma unroll
            for (int m = 0; m < 4; m++)
#pragma unroll
                for (int n = 0; n < 4; n++)
                    acc[m][n] = __builtin_amdgcn_mfma_f32_16x16x32_bf16(af[m], bg[n], acc[m][n], 0, 0, 0);
        }
        __syncthreads();         // all waves done reading this tile
        if (kn < 512) {
            g1_write(As, Bs, t, fr, vb);   // vmcnt wait happens here, after MFMA
        }
        __syncthreads();
    }
    // epilogue: C/D layout col=lane&15, row=(lane>>4)*4+j  [m89-verified]
#pragma unroll
    for (int m = 0; m < 4; m++) {
#pragma unroll
        for (int j = 0; j < 4; j++) {
            int row = bm + wr * 64 + m * 16 + (l >> 4) * 4 + j;
            if (row < M) {
#pragma unroll
                for (int n = 0; n < 4; n++) {
                    int col = wc * 64 + n * 16 + (l & 15);
                    C[(size_t)row * 256 + col] = f2bf(acc[m][n][j]);
                }
            }
        }
    }
}

// ---------------- aggregation layer 1: unroll-4 gather ILP, fp32 accum, +bias, relu -> bf16 ----------------
__global__ void agg1_kernel(const unsigned short* __restrict__ h, const float* __restrict__ dinv,
                            const int* __restrict__ rp, const int* __restrict__ csrc,
                            const float* __restrict__ bias, unsigned short* __restrict__ out, int n) {
    int wave = (blockIdx.x * blockDim.x + threadIdx.x) >> 6;
    int lane = threadIdx.x & 63;
    if (wave >= n) return;
    int v = wave;
    float dv = dinv[v];
    ushort4 sv = ((const ushort4*)(h + (size_t)v * 256))[lane];
    float a0 = bf2f(sv.x) * dv, a1 = bf2f(sv.y) * dv, a2 = bf2f(sv.z) * dv, a3 = bf2f(sv.w) * dv;
    int b0 = rp[v], b1e = rp[v + 1];
    int i = b0;
    for (; i + 4 <= b1e; i += 4) {   // 4 independent gathers in flight
        int s0 = csrc[i], s1 = csrc[i + 1], s2 = csrc[i + 2], s3 = csrc[i + 3];
        float d0 = dinv[s0], d1 = dinv[s1], d2 = dinv[s2], d3 = dinv[s3];
        ushort4 r0 = ((const ushort4*)(h + (size_t)s0 * 256))[lane];
        ushort4 r1 = ((const ushort4*)(h + (size_t)s1 * 256))[lane];
        ushort4 r2 = ((const ushort4*)(h + (size_t)s2 * 256))[lane];
        ushort4 r3 = ((const ushort4*)(h + (size_t)s3 * 256))[lane];
        a0 += bf2f(r0.x) * d0 + bf2f(r1.x) * d1 + bf2f(r2.x) * d2 + bf2f(r3.x) * d3;
        a1 += bf2f(r0.y) * d0 + bf2f(r1.y) * d1 + bf2f(r2.y) * d2 + bf2f(r3.y) * d3;
        a2 += bf2f(r0.z) * d0 + bf2f(r1.z) * d1 + bf2f(r2.z) * d2 + bf2f(r3.z) * d3;
        a3 += bf2f(r0.w) * d0 + bf2f(r1.w) * d1 + bf2f(r2.w) * d2 + bf2f(r3.w) * d3;
    }
    for (; i < b1e; i++) {
        int s = csrc[i];
        float ds = dinv[s];
        ushort4 hs = ((const ushort4*)(h + (size_t)s * 256))[lane];
        a0 += bf2f(hs.x) * ds; a1 += bf2f(hs.y) * ds;
        a2 += bf2f(hs.z) * ds; a3 += bf2f(hs.w) * ds;
    }
    float4 bb = ((const float4*)bias)[lane];
    ushort4 ov;
    ov.x = f2bf(fmaxf(a0 * dv + bb.x, 0.f));
    ov.y = f2bf(fmaxf(a1 * dv + bb.y, 0.f));
    ov.z = f2bf(fmaxf(a2 * dv + bb.z, 0.f));
    ov.w = f2bf(fmaxf(a3 * dv + bb.w, 0.f));
    ((ushort4*)(out + (size_t)v * 256))[lane] = ov;
}

// ---------------- GEMM2 (MFMA bf16, 2-phase pipelined): h2 = h1a @ W2, K=256 N=64 ----------------
#define G2_BM 256
#define G2_BN 64
#define G2_BK 64

__device__ __forceinline__ void g2_loadA(const unsigned short* __restrict__ A, int bm, int M,
                                         int t, int k0, uint4 (&va)[4]) {
#pragma unroll
    for (int j = 0; j < 4; j++) {
        int c = j * 512 + t;
        int row = c >> 3, slot = c & 7;
        int R = bm + row;
        uint4 z = {0, 0, 0, 0};
        va[j] = (R < M) ? *(const uint4*)(A + (size_t)R * 256 + k0 + slot * 8) : z;
    }
}

__device__ __forceinline__ void g2_write(char* As, char* Bs, int t,
                                         const uint4 (&va)[4], const uint4& vbv) {
#pragma unroll
    for (int j = 0; j < 4; j++) {
        int c = j * 512 + t;
        int row = c >> 3, slot = c & 7;
        *(uint4*)(As + row * 128 + ((slot ^ (row & 7)) * 16)) = va[j];
    }
    {
        int col = t >> 3, slot = t & 7;
        *(uint4*)(Bs + col * 128 + ((slot ^ (col & 7)) * 16)) = vbv;
    }
}

__launch_bounds__(512)
__global__ void gemm2_mfma(const unsigned short* __restrict__ A,   // h1a bf16 [M][256]
                           const unsigned short* __restrict__ Bt,  // W2t [64][256] bf16
                           float* __restrict__ C,                  // h2 [M][64] fp32
                           int M) {
    __shared__ char lds[(G2_BM + G2_BN) * G2_BK * 2];  // As 32KB + Bs 8KB
    char* As = lds;
    char* Bs = lds + G2_BM * G2_BK * 2;
    const int t = threadIdx.x;
    const int l = t & 63;
    const int w = t >> 6;                 // wave row 0..7
    const int bm = blockIdx.x * G2_BM;

    f32x4 acc[2][4] = {};
    uint4 va[4], vbv;

    g2_loadA(A, bm, M, t, 0, va);
    vbv = *(const uint4*)(Bt + (size_t)(t >> 3) * 256 + (t & 7) * 8);
    g2_write(As, Bs, t, va, vbv);
    __syncthreads();

    for (int k0 = 0; k0 < 256; k0 += G2_BK) {
        int kn = k0 + G2_BK;
        if (kn < 256) {
            g2_loadA(A, bm, M, t, kn, va);
            vbv = *(const uint4*)(Bt + (size_t)(t >> 3) * 256 + kn + (t & 7) * 8);
        }
#pragma unroll
        for (int kk = 0; kk < 2; kk++) {
            bf16x8 af[2], bg[4];
#pragma unroll
            for (int m = 0; m < 2; m++) {
                int row = w * 32 + m * 16 + (l & 15);
                int slot = kk * 4 + (l >> 4);
                af[m] = *(const bf16x8*)(As + row * 128 + ((slot ^ (row & 7)) * 16));
            }
#pragma unroll
            for (int n = 0; n < 4; n++) {
                int col = n * 16 + (l & 15);
                int slot = kk * 4 + (l >> 4);
                bg[n] = *(const bf16x8*)(Bs + col * 128 + ((slot ^ (col & 7)) * 16));
            }
#pragma unroll
            for (int m = 0; m < 2; m++)
#pragma unroll
                for (int n = 0; n < 4; n++)
                    acc[m][n] = __builtin_amdgcn_mfma_f32_16x16x32_bf16(af[m], bg[n], acc[m][n], 0, 0, 0);
        }
        __syncthreads();
        if (kn < 256) {
            g2_write(As, Bs, t, va, vbv);
        }
        __syncthreads();
    }
#pragma unroll
    for (int m = 0; m < 2; m++) {
#pragma unroll
        for (int j = 0; j < 4; j++) {
            int row = bm + w * 32 + m * 16 + (l >> 4) * 4 + j;
            if (row < M) {
#pragma unroll
                for (int n = 0; n < 4; n++) {
                    int col = n * 16 + (l & 15);
                    C[(size_t)row * 64 + col] = acc[m][n][j];
                }
            }
        }
    }
}

// ---------------- agg2 + heads fused: aggregate h2, relu, then p[v]=h@WW, outB[v]=h@WB+bB ----------------
__global__ void agg2heads_kernel(const float* __restrict__ h, const float* __restrict__ dinv,
                                 const int* __restrict__ rp, const int* __restrict__ csrc,
                                 const float* __restrict__ bias,
                                 const float* __restrict__ WW, const float* __restrict__ WB,
                                 const float* __restrict__ bB,
                                 float* __restrict__ p, float* __restrict__ outB, int n) {
    int wave = (blockIdx.x * blockDim.x + threadIdx.x) >> 6;
    int lane = threadIdx.x & 63;
    if (wave >= n) return;
    int v = wave;
    float dv = dinv[v];
    float acc = h[(size_t)v * 64 + lane] * dv;
    int b0 = rp[v], b1e = rp[v + 1];
    int i = b0;
    for (; i + 4 <= b1e; i += 4) {   // 4 independent gathers in flight
        int s0 = csrc[i], s1 = csrc[i + 1], s2 = csrc[i + 2], s3 = csrc[i + 3];
        float d0 = dinv[s0], d1 = dinv[s1], d2 = dinv[s2], d3 = dinv[s3];
        float r0 = h[(size_t)s0 * 64 + lane];
        float r1 = h[(size_t)s1 * 64 + lane];
        float r2 = h[(size_t)s2 * 64 + lane];
        float r3 = h[(size_t)s3 * 64 + lane];
        acc += r0 * d0 + r1 * d1 + r2 * d2 + r3 * d3;
    }
    for (; i < b1e; i++) {
        int s = csrc[i];
        acc += h[(size_t)s * 64 + lane] * dinv[s];
    }
    float hv = fmaxf(acc * dv + bias[lane], 0.f);
    float pw = hv * WW[lane];
    float pb = hv * WB[lane];
#pragma unroll
    for (int off = 32; off >= 1; off >>= 1) {
        pw += __shfl_xor(pw, off);
        pb += __shfl_xor(pb, off);
    }
    if (lane == 0) {
        p[v] = pw;
        outB[v] = pb + bB[0];
    }
}

__global__ void weights_kernel(const int* __restrict__ src, const int* __restrict__ dst,
                               const float* __restrict__ p, const float* __restrict__ bW,
                               float* __restrict__ outW, int n) {
    int i = blockIdx.x * blockDim.x + threadIdx.x;
    if (i < n) {
        int e = 2 * i;
        outW[i] = 0.5f * (p[src[e]] + p[dst[e]]) + bW[0];
    }
}

// ---------------- launch ----------------

extern "C" void kernel_launch(void* const* d_in, const int* in_sizes, int n_in,
                              void* d_out, int out_size, void* d_ws, size_t ws_size,
                              hipStream_t stream) {
    const float* x  = (const float*)d_in[0];
    const int*   ei = (const int*)d_in[1];
    const int*   src = ei;
    const int*   dst = ei + NE;
    const float* W1 = (const float*)d_in[2];
    const float* b1 = (const float*)d_in[3];
    const float* W2 = (const float*)d_in[4];
    const float* b2 = (const float*)d_in[5];
    const float* WB = (const float*)d_in[6];
    const float* bB = (const float*)d_in[7];
    const float* WW = (const float*)d_in[8];
    const float* bW = (const float*)d_in[9];
    float* outW = (float*)d_out;          // 500000 weights
    float* outB = (float*)d_out + 500000; // 100000 biases

    char* ws = (char*)d_ws;
    unsigned short* h1b = (unsigned short*)(ws);               // [100000][256] bf16 = 51.2MB
    unsigned short* h1a = (unsigned short*)(ws + 51200000);    // [100000][256] bf16 = 51.2MB
    float* h2  = (float*)(ws);                                 // overlays dead h1b, 25.6MB
    float* p   = (float*)(ws + 153600000);                     // 400KB
    char* tail = ws + 155000000;
    float* dinv = (float*)(tail);                              // 400,000
    int*   rp   = (int*)(tail + 400000);                       // 400,064
    int*   cnt  = (int*)(tail + 800064);                       // 400,000
    int*   fill = (int*)(tail + 1200064);                      // 400,000
    int*   csrc = (int*)(tail + 1600064);                      // 4,000,000
    int*   tmp  = (int*)(tail + 5600064);                      // 400,000
    int*   bsum = (int*)(tail + 6000064);                      // 512
    unsigned short* W1t = (unsigned short*)(tail + 6000576);   // 262,144 bf16 = 524,288 B
    unsigned short* W2t = (unsigned short*)(tail + 6524864);   // 16,384 bf16 = 32,768 B

    hipMemsetAsync(cnt, 0, 800000, stream);  // cnt + fill (contiguous)

    count_kernel<<<(NE + 255) / 256, 256, 0, stream>>>(dst, cnt, NE);
    dinv_kernel<<<(NN + 255) / 256, 256, 0, stream>>>(cnt, dinv, NN);
    int nblk = (NN + 1023) / 1024;  // 98
    scan1_kernel<<<nblk, 1024, 0, stream>>>(cnt, tmp, bsum, NN);
    scan2_kernel<<<1, 128, 0, stream>>>(bsum, nblk);
    scan3_kernel<<<nblk, 1024, 0, stream>>>(tmp, cnt, bsum, rp, NN);
    fill_kernel<<<(NE + 255) / 256, 256, 0, stream>>>(src, dst, rp, fill, csrc, NE);

    convW1t_kernel<<<(256 * 512 + 255) / 256, 256, 0, stream>>>(W1, W1t);
    convW2t_kernel<<<(64 * 256 + 255) / 256, 256, 0, stream>>>(W2, W2t);
    gemm1_mfma<<<(NN + G1_BM - 1) / G1_BM, 512, 0, stream>>>(x, W1t, h1b, NN);
    agg1_kernel<<<(NN + 3) / 4, 256, 0, stream>>>(h1b, dinv, rp, csrc, b1, h1a, NN);

    gemm2_mfma<<<(NN + G2_BM - 1) / G2_BM, 512, 0, stream>>>(h1a, W2t, h2, NN);
    agg2heads_kernel<<<(NN + 3) / 4, 256, 0, stream>>>(h2, dinv, rp, csrc, b2, WW, WB, bB, p, outB, NN);

    weights_kernel<<<(500000 + 255) / 256, 256, 0, stream>>>(src, dst, p, bW, outW, 500000);
}